// Round 1
// baseline (1313.601 us; speedup 1.0000x reference)
//
#include <hip/hip_runtime.h>
#include <math.h>

// Problem constants (from reference): B=4, N=1024, C=512, H=8, D=64
// ws layout (floats): q[B*H*N*D] | kT[B*H*D*N] | v[B*H*N*D] | apos[B*N*64]

// ---------------- kernel 0: apos = pos @ w1  ([B*N,3]@[3,64]) ----------------
__global__ __launch_bounds__(256) void pos_w1_kernel(
    const float* __restrict__ pos, const float* __restrict__ w1,
    float* __restrict__ apos)
{
    const int idx = blockIdx.x * 256 + threadIdx.x;   // < 4096*64
    const int bn = idx >> 6, j = idx & 63;
    const float px = pos[bn * 3 + 0];
    const float py = pos[bn * 3 + 1];
    const float pz = pos[bn * 3 + 2];
    apos[idx] = fmaf(px, w1[j], fmaf(py, w1[64 + j], pz * w1[128 + j]));
}

// ---------------- kernel 1: qkv projection GEMM (fp32, 128x128x8) ------------
// x[4096,512] @ w[512,1536] + b -> scatter into q[B,H,N,D], kT[B,H,D,N], v[B,H,N,D]
__global__ __launch_bounds__(256) void qkv_gemm(
    const float* __restrict__ x, const float* __restrict__ wqkv,
    const float* __restrict__ bqkv,
    float* __restrict__ q, float* __restrict__ kT, float* __restrict__ v)
{
    __shared__ __align__(16) float As[8][128];
    __shared__ __align__(16) float Bs[8][128];
    const int tid = threadIdx.x;
    const int m0 = blockIdx.x * 128;
    const int n0 = blockIdx.y * 128;
    const int tx = tid & 15;
    const int ty = tid >> 4;
    const int ar = tid >> 1, ak = (tid & 1) * 4;
    const int br = tid >> 5, bc = (tid & 31) * 4;

    float acc[8][8];
#pragma unroll
    for (int r = 0; r < 8; ++r)
#pragma unroll
        for (int c = 0; c < 8; ++c) acc[r][c] = 0.f;

    for (int k0 = 0; k0 < 512; k0 += 8) {
        const float4 av = *(const float4*)&x[(size_t)(m0 + ar) * 512 + k0 + ak];
        const float4 bv = *(const float4*)&wqkv[(size_t)(k0 + br) * 1536 + n0 + bc];
        __syncthreads();
        As[ak + 0][ar] = av.x;
        As[ak + 1][ar] = av.y;
        As[ak + 2][ar] = av.z;
        As[ak + 3][ar] = av.w;
        *(float4*)&Bs[br][bc] = bv;
        __syncthreads();
#pragma unroll
        for (int kk = 0; kk < 8; ++kk) {
            const float4 a0 = *(const float4*)&As[kk][ty * 8];
            const float4 a1 = *(const float4*)&As[kk][ty * 8 + 4];
            const float4 b0 = *(const float4*)&Bs[kk][tx * 8];
            const float4 b1v = *(const float4*)&Bs[kk][tx * 8 + 4];
            const float ar_[8] = {a0.x, a0.y, a0.z, a0.w, a1.x, a1.y, a1.z, a1.w};
            const float bc_[8] = {b0.x, b0.y, b0.z, b0.w, b1v.x, b1v.y, b1v.z, b1v.w};
#pragma unroll
            for (int r = 0; r < 8; ++r)
#pragma unroll
                for (int c = 0; c < 8; ++c)
                    acc[r][c] = fmaf(ar_[r], bc_[c], acc[r][c]);
        }
    }

#pragma unroll
    for (int r = 0; r < 8; ++r) {
        const int row = m0 + ty * 8 + r;
        const int b = row >> 10, n = row & 1023;
#pragma unroll
        for (int c = 0; c < 8; ++c) {
            const int col = n0 + tx * 8 + c;
            const float val = acc[r][c] + bqkv[col];
            const int s = col >> 9;
            const int h = (col >> 6) & 7;
            const int d = col & 63;
            if (s == 0)
                q[(size_t)((b * 8 + h) * 1024 + n) * 64 + d] = val;
            else if (s == 1)
                kT[(size_t)((b * 8 + h) * 64 + d) * 1024 + n] = val;
            else
                v[(size_t)((b * 8 + h) * 1024 + n) * 64 + d] = val;
        }
    }
}

// ---------------- kernel 2: fused bias-MLP + flash attention -----------------
// block = (b, 16-query tile); 8 waves, wave w == head w; key tiles of 64.
__global__ __launch_bounds__(512) void attn_fused(
    const float* __restrict__ q, const float* __restrict__ kT,
    const float* __restrict__ v, const float* __restrict__ apos,
    const float* __restrict__ pos, const float* __restrict__ b1,
    const float* __restrict__ w2, const float* __restrict__ b2,
    float* __restrict__ out)
{
    const int bx = blockIdx.x;          // 256 blocks
    const int b = bx >> 6;
    const int nq0 = (bx & 63) * 16;
    const int tid = threadIdx.x;
    const int w = tid >> 6;             // wave id == head
    const int lane = tid & 63;

    __shared__ __align__(16) float q_s[8][16][64];    // 32 KB
    __shared__ __align__(16) float bias_s[8][16][68]; // 34.8 KB (padded)
    __shared__ __align__(16) float p_s[8][16][64];    // 32 KB
    __shared__ __align__(16) float a_m_s[64][68];     // 17.4 KB (padded)
    __shared__ __align__(16) float a_n_s[16][68];     // 4.35 KB (padded)
    __shared__ __align__(16) float pos_q_s[16][4];
    __shared__ __align__(16) float pos_k_s[64][4];
    __shared__ __align__(16) float b1_s[64];
    __shared__ __align__(16) float w2_s[64][8];
    __shared__ __align__(16) float b2_s[8];

    // ---- one-time cooperative loads ----
    {
        float* qf = &q_s[0][0][0];
        for (int f = tid * 4; f < 8192; f += 2048) {
            const int h = f >> 10, i = (f >> 6) & 15, d = f & 63;
            *(float4*)&qf[f] =
                *(const float4*)&q[(size_t)((b * 8 + h) * 1024 + nq0 + i) * 64 + d];
        }
        if (tid < 256) {
            const int i = tid >> 4, j4 = (tid & 15) * 4;
            *(float4*)&a_n_s[i][j4] =
                *(const float4*)&apos[(size_t)(b * 1024 + nq0 + i) * 64 + j4];
        }
        if (tid < 48) {
            const int i = tid / 3, c = tid % 3;
            pos_q_s[i][c] = pos[(size_t)(b * 1024 + nq0 + i) * 3 + c];
        }
        if (tid < 64) b1_s[tid] = b1[tid];
        (&w2_s[0][0])[tid] = w2[tid];   // 512 threads, 512 floats, same layout
        if (tid < 8) b2_s[tid] = b2[tid];
    }

    float m_i[16], l_i[16], o_acc[16];
#pragma unroll
    for (int i = 0; i < 16; ++i) {
        m_i[i] = -INFINITY;
        l_i[i] = 0.f;
        o_acc[i] = 0.f;
    }

    const float* kTb = kT + (size_t)((b * 8 + w) * 64) * 1024 + lane;
    const float* vb = v + (size_t)((b * 8 + w) * 1024) * 64 + lane;

    for (int mt = 0; mt < 16; ++mt) {
        const int m0 = mt * 64;
        __syncthreads();  // previous tile's consumers done (also covers init loads)

        // ---- cooperative: stage a_m, pos_k for this key tile ----
        for (int f = tid * 4; f < 4096; f += 2048) {
            const int j = f >> 6, jj = f & 63;
            *(float4*)&a_m_s[j][jj] =
                *(const float4*)&apos[(size_t)(b * 1024 + m0 + j) * 64 + jj];
        }
        if (tid < 192) {
            const int j = tid / 3, c = tid % 3;
            pos_k_s[j][c] = pos[(size_t)(b * 1024 + m0 + j) * 3 + c];
        }
        __syncthreads();

        // ---- cooperative bias MLP: 1024 pairs, 2 per thread ----
#pragma unroll
        for (int it = 0; it < 2; ++it) {
            const int i = lane & 15;
            const int j = it * 32 + w * 4 + (lane >> 4);
            const float dx = pos_q_s[i][0] - pos_k_s[j][0];
            const float dy = pos_q_s[i][1] - pos_k_s[j][1];
            const float dz = pos_q_s[i][2] - pos_k_s[j][2];
            const float inv =
                1.f / (sqrtf(fmaf(dx, dx, fmaf(dy, dy, dz * dz))) + 1e-6f);
            float acc8[8];
#pragma unroll
            for (int h = 0; h < 8; ++h) acc8[h] = b2_s[h];
#pragma unroll
            for (int jj0 = 0; jj0 < 64; jj0 += 4) {
                const float4 an = *(const float4*)&a_n_s[i][jj0];
                const float4 am = *(const float4*)&a_m_s[j][jj0];
                const float4 bb = *(const float4*)&b1_s[jj0];
                float hv[4];
                hv[0] = fmaxf(fmaf(an.x - am.x, inv, bb.x), 0.f);
                hv[1] = fmaxf(fmaf(an.y - am.y, inv, bb.y), 0.f);
                hv[2] = fmaxf(fmaf(an.z - am.z, inv, bb.z), 0.f);
                hv[3] = fmaxf(fmaf(an.w - am.w, inv, bb.w), 0.f);
#pragma unroll
                for (int u = 0; u < 4; ++u) {
                    const float4 w2a = *(const float4*)&w2_s[jj0 + u][0];
                    const float4 w2b = *(const float4*)&w2_s[jj0 + u][4];
                    acc8[0] = fmaf(hv[u], w2a.x, acc8[0]);
                    acc8[1] = fmaf(hv[u], w2a.y, acc8[1]);
                    acc8[2] = fmaf(hv[u], w2a.z, acc8[2]);
                    acc8[3] = fmaf(hv[u], w2a.w, acc8[3]);
                    acc8[4] = fmaf(hv[u], w2b.x, acc8[4]);
                    acc8[5] = fmaf(hv[u], w2b.y, acc8[5]);
                    acc8[6] = fmaf(hv[u], w2b.z, acc8[6]);
                    acc8[7] = fmaf(hv[u], w2b.w, acc8[7]);
                }
            }
#pragma unroll
            for (int h = 0; h < 8; ++h) bias_s[h][i][j] = acc8[h];
        }
        __syncthreads();

        // ---- per-wave QK^T (lane = key j) ----
        float s_acc[16];
#pragma unroll
        for (int i = 0; i < 16; ++i) s_acc[i] = 0.f;
        const float* kp = kTb + m0;
        for (int d0 = 0; d0 < 64; d0 += 4) {
            const float k0v = kp[(size_t)(d0 + 0) * 1024];
            const float k1v = kp[(size_t)(d0 + 1) * 1024];
            const float k2v = kp[(size_t)(d0 + 2) * 1024];
            const float k3v = kp[(size_t)(d0 + 3) * 1024];
#pragma unroll
            for (int i = 0; i < 16; ++i) {
                const float4 q4 = *(const float4*)&q_s[w][i][d0];
                s_acc[i] = fmaf(q4.x, k0v, s_acc[i]);
                s_acc[i] = fmaf(q4.y, k1v, s_acc[i]);
                s_acc[i] = fmaf(q4.z, k2v, s_acc[i]);
                s_acc[i] = fmaf(q4.w, k3v, s_acc[i]);
            }
        }

        // ---- online softmax (per query row, reduce across 64 lanes) ----
#pragma unroll
        for (int i = 0; i < 16; ++i) {
            const float sv = fmaf(s_acc[i], 0.125f, bias_s[w][i][lane]);
            float mx = sv;
#pragma unroll
            for (int off = 32; off > 0; off >>= 1)
                mx = fmaxf(mx, __shfl_xor(mx, off, 64));
            const float mnew = fmaxf(m_i[i], mx);
            const float p = __expf(sv - mnew);
            float rs = p;
#pragma unroll
            for (int off = 32; off > 0; off >>= 1) rs += __shfl_xor(rs, off, 64);
            const float alpha = __expf(m_i[i] - mnew);
            l_i[i] = fmaf(l_i[i], alpha, rs);
            o_acc[i] *= alpha;
            m_i[i] = mnew;
            p_s[w][i][lane] = p;
        }

        // ---- per-wave PV (lane = output dim d) ----
        const float* vp = vb + (size_t)m0 * 64;
        for (int j0 = 0; j0 < 64; j0 += 4) {
            const float v0 = vp[(size_t)(j0 + 0) * 64];
            const float v1 = vp[(size_t)(j0 + 1) * 64];
            const float v2 = vp[(size_t)(j0 + 2) * 64];
            const float v3 = vp[(size_t)(j0 + 3) * 64];
#pragma unroll
            for (int i = 0; i < 16; ++i) {
                const float4 p4 = *(const float4*)&p_s[w][i][j0];
                o_acc[i] = fmaf(p4.x, v0, o_acc[i]);
                o_acc[i] = fmaf(p4.y, v1, o_acc[i]);
                o_acc[i] = fmaf(p4.z, v2, o_acc[i]);
                o_acc[i] = fmaf(p4.w, v3, o_acc[i]);
            }
        }
    }

    // ---- epilogue: out[b, n, h*64+d] ----
#pragma unroll
    for (int i = 0; i < 16; ++i) {
        out[(size_t)(b * 1024 + nq0 + i) * 512 + w * 64 + lane] =
            o_acc[i] / l_i[i];
    }
}

extern "C" void kernel_launch(void* const* d_in, const int* in_sizes, int n_in,
                              void* d_out, int out_size, void* d_ws, size_t ws_size,
                              hipStream_t stream) {
    const float* x    = (const float*)d_in[0];
    const float* pos  = (const float*)d_in[1];
    const float* wqkv = (const float*)d_in[2];
    const float* bqkv = (const float*)d_in[3];
    const float* w1   = (const float*)d_in[4];
    const float* b1   = (const float*)d_in[5];
    const float* w2   = (const float*)d_in[6];
    const float* b2   = (const float*)d_in[7];
    float* out = (float*)d_out;
    float* ws = (float*)d_ws;

    float* q    = ws;             // 2,097,152 floats
    float* kT   = ws + 2097152;   // 2,097,152
    float* v    = ws + 4194304;   // 2,097,152
    float* apos = ws + 6291456;   // 262,144   (total 26.2 MB)

    hipLaunchKernelGGL(pos_w1_kernel, dim3(1024), dim3(256), 0, stream,
                       pos, w1, apos);
    hipLaunchKernelGGL(qkv_gemm, dim3(32, 12), dim3(256), 0, stream,
                       x, wqkv, bqkv, q, kT, v);
    hipLaunchKernelGGL(attn_fused, dim3(256), dim3(512), 0, stream,
                       q, kT, v, apos, pos, b1, w2, b2, out);
}

// Round 2
// 1251.413 us; speedup vs baseline: 1.0497x; 1.0497x over previous
//
#include <hip/hip_runtime.h>
#include <math.h>

// B=4, N=1024, C=512, H=8, D=64
// ws (floats): q[2097152] | kT[2097152] | v[2097152] | apos[262144]  (25.2 MB)
// d_out doubles as scratch for the un-transposed k ("kk", 2097152 floats) --
// it is fully overwritten by attn_fused at the end.

// ---------------- kernel 0: apos = pos @ w1 ----------------
__global__ __launch_bounds__(256) void pos_w1_kernel(
    const float* __restrict__ pos, const float* __restrict__ w1,
    float* __restrict__ apos)
{
    const int idx = blockIdx.x * 256 + threadIdx.x;   // < 4096*64
    const int bn = idx >> 6, j = idx & 63;
    const float px = pos[bn * 3 + 0];
    const float py = pos[bn * 3 + 1];
    const float pz = pos[bn * 3 + 2];
    apos[idx] = fmaf(px, w1[j], fmaf(py, w1[64 + j], pz * w1[128 + j]));
}

// ---------------- kernel 1: qkv projection GEMM (fp32, 128x128x8) ------------
// scatter: q[B,H,N,D] coalesced, kk[B,H,N,D] coalesced (into d_out scratch),
// v[B,H,N,D] coalesced.
__global__ __launch_bounds__(256) void qkv_gemm(
    const float* __restrict__ x, const float* __restrict__ wqkv,
    const float* __restrict__ bqkv,
    float* __restrict__ q, float* __restrict__ kk, float* __restrict__ v)
{
    __shared__ __align__(16) float As[8][128];
    __shared__ __align__(16) float Bs[8][128];
    const int tid = threadIdx.x;
    const int m0 = blockIdx.x * 128;
    const int n0 = blockIdx.y * 128;
    const int tx = tid & 15;
    const int ty = tid >> 4;
    const int ar = tid >> 1, ak = (tid & 1) * 4;
    const int br = tid >> 5, bc = (tid & 31) * 4;

    float acc[8][8];
#pragma unroll
    for (int r = 0; r < 8; ++r)
#pragma unroll
        for (int c = 0; c < 8; ++c) acc[r][c] = 0.f;

    for (int k0 = 0; k0 < 512; k0 += 8) {
        const float4 av = *(const float4*)&x[(size_t)(m0 + ar) * 512 + k0 + ak];
        const float4 bv = *(const float4*)&wqkv[(size_t)(k0 + br) * 1536 + n0 + bc];
        __syncthreads();
        As[ak + 0][ar] = av.x;
        As[ak + 1][ar] = av.y;
        As[ak + 2][ar] = av.z;
        As[ak + 3][ar] = av.w;
        *(float4*)&Bs[br][bc] = bv;
        __syncthreads();
#pragma unroll
        for (int kk_ = 0; kk_ < 8; ++kk_) {
            const float4 a0 = *(const float4*)&As[kk_][ty * 8];
            const float4 a1 = *(const float4*)&As[kk_][ty * 8 + 4];
            const float4 b0 = *(const float4*)&Bs[kk_][tx * 8];
            const float4 b1v = *(const float4*)&Bs[kk_][tx * 8 + 4];
            const float ar_[8] = {a0.x, a0.y, a0.z, a0.w, a1.x, a1.y, a1.z, a1.w};
            const float bc_[8] = {b0.x, b0.y, b0.z, b0.w, b1v.x, b1v.y, b1v.z, b1v.w};
#pragma unroll
            for (int r = 0; r < 8; ++r)
#pragma unroll
                for (int c = 0; c < 8; ++c)
                    acc[r][c] = fmaf(ar_[r], bc_[c], acc[r][c]);
        }
    }

#pragma unroll
    for (int r = 0; r < 8; ++r) {
        const int row = m0 + ty * 8 + r;
        const int b = row >> 10, n = row & 1023;
#pragma unroll
        for (int c = 0; c < 8; ++c) {
            const int col = n0 + tx * 8 + c;
            const float val = acc[r][c] + bqkv[col];
            const int s = col >> 9;
            const int h = (col >> 6) & 7;
            const int d = col & 63;
            const size_t off = (size_t)((b * 8 + h) * 1024 + n) * 64 + d;
            if (s == 0)
                q[off] = val;
            else if (s == 1)
                kk[off] = val;
            else
                v[off] = val;
        }
    }
}

// ---------------- kernel 1b: kT[b,h,d,n] = kk[b,h,n,d] (LDS tiled) -----------
__global__ __launch_bounds__(256) void kt_transpose(
    const float* __restrict__ kk, float* __restrict__ kT)
{
    __shared__ float tile[64][65];
    const int bh = blockIdx.x;          // 0..31
    const int n0 = blockIdx.y * 64;     // 0..960
    const int tid = threadIdx.x;
    const int c = tid & 63;
    const int r4 = tid >> 6;            // 0..3
    const size_t base = (size_t)bh * 65536;
#pragma unroll
    for (int rr = 0; rr < 16; ++rr) {
        const int row = rr * 4 + r4;    // n offset
        tile[row][c] = kk[base + (size_t)(n0 + row) * 64 + c];
    }
    __syncthreads();
#pragma unroll
    for (int ww = 0; ww < 16; ++ww) {
        const int d = ww * 4 + r4;
        kT[base + (size_t)d * 1024 + n0 + c] = tile[c][d];
    }
}

// ---------------- kernel 2: fused bias-MLP + flash attention -----------------
// block = (batch, 16-query tile); 8 waves, wave w == head w; key tiles of 64.
// XCD swizzle: xcd = blockIdx.x % 8 (assumed), each XCD serves one batch.
__global__ __launch_bounds__(512, 2) void attn_fused(
    const float* __restrict__ q, const float* __restrict__ kT,
    const float* __restrict__ v, const float* __restrict__ apos,
    const float* __restrict__ pos, const float* __restrict__ b1,
    const float* __restrict__ w2, const float* __restrict__ b2,
    float* __restrict__ out)
{
    // ---- XCD-aware remap: batch = xcd/2, so each XCD's L2 holds one batch's KV
    const int bx = blockIdx.x;          // 0..255
    const int xcd = bx & 7;
    const int slot = bx >> 3;           // 0..31
    const int b = xcd >> 1;             // 0..3
    const int t = slot * 2 + (xcd & 1); // 0..63
    const int nq0 = t * 16;

    const int tid = threadIdx.x;
    const int w = tid >> 6;             // wave id == head
    const int lane = tid & 63;

    __shared__ __align__(16) float q_s[8][16][64];    // 32 KB (pre-scaled)
    __shared__ __align__(16) float bias_s[8][16][68]; // 34.8 KB; re-used as p
    __shared__ __align__(16) float a_m_s[64][68];     // 17.4 KB
    __shared__ __align__(16) float a_n_s[16][68];     // 4.35 KB
    __shared__ __align__(16) float pos_q_s[16][4];
    __shared__ __align__(16) float pos_k_s[64][4];
    __shared__ __align__(16) float b1_s[64];
    __shared__ __align__(16) float w2_s[64][8];
    __shared__ __align__(16) float b2_s[8];

    // ---- one-time cooperative loads ----
    {
        float* qf = &q_s[0][0][0];
        for (int f = tid * 4; f < 8192; f += 2048) {
            const int h = f >> 10, i = (f >> 6) & 15, d = f & 63;
            float4 qv =
                *(const float4*)&q[(size_t)((b * 8 + h) * 1024 + nq0 + i) * 64 + d];
            qv.x *= 0.125f; qv.y *= 0.125f; qv.z *= 0.125f; qv.w *= 0.125f;
            *(float4*)&qf[f] = qv;
        }
        if (tid < 256) {
            const int i = tid >> 4, j4 = (tid & 15) * 4;
            *(float4*)&a_n_s[i][j4] =
                *(const float4*)&apos[(size_t)(b * 1024 + nq0 + i) * 64 + j4];
        }
        if (tid < 48) {
            const int i = tid / 3, c = tid % 3;
            pos_q_s[i][c] = pos[(size_t)(b * 1024 + nq0 + i) * 3 + c];
        }
        if (tid < 64) b1_s[tid] = b1[tid];
        (&w2_s[0][0])[tid] = w2[tid];
        if (tid < 8) b2_s[tid] = b2[tid];
    }

    float m_i[16], l_i[16], o_acc[16];
#pragma unroll
    for (int i = 0; i < 16; ++i) {
        m_i[i] = -INFINITY;
        l_i[i] = 0.f;
        o_acc[i] = 0.f;
    }

    const float* kTb = kT + (size_t)((b * 8 + w) * 64) * 1024 + lane;
    const float* vb = v + (size_t)((b * 8 + w) * 1024) * 64 + lane;

    for (int mt = 0; mt < 16; ++mt) {
        const int m0 = mt * 64;
        __syncthreads();  // prev-phase p/bias consumers done

        // ---- stage a_m, pos_k ----
        for (int f = tid * 4; f < 4096; f += 2048) {
            const int j = f >> 6, jj = f & 63;
            *(float4*)&a_m_s[j][jj] =
                *(const float4*)&apos[(size_t)(b * 1024 + m0 + j) * 64 + jj];
        }
        if (tid < 192) {
            const int j = tid / 3, c = tid % 3;
            pos_k_s[j][c] = pos[(size_t)(b * 1024 + m0 + j) * 3 + c];
        }
        __syncthreads();

        // ---- cooperative bias MLP: 1024 pairs, 2 per thread ----
#pragma unroll
        for (int it = 0; it < 2; ++it) {
            const int i = lane & 15;
            const int j = it * 32 + w * 4 + (lane >> 4);
            const float dx = pos_q_s[i][0] - pos_k_s[j][0];
            const float dy = pos_q_s[i][1] - pos_k_s[j][1];
            const float dz = pos_q_s[i][2] - pos_k_s[j][2];
            const float inv =
                1.f / (sqrtf(fmaf(dx, dx, fmaf(dy, dy, dz * dz))) + 1e-6f);
            float acc8[8];
#pragma unroll
            for (int h = 0; h < 8; ++h) acc8[h] = b2_s[h];
#pragma unroll
            for (int jj0 = 0; jj0 < 64; jj0 += 4) {
                const float4 an = *(const float4*)&a_n_s[i][jj0];
                const float4 am = *(const float4*)&a_m_s[j][jj0];
                const float4 bb = *(const float4*)&b1_s[jj0];
                float hv[4];
                hv[0] = fmaxf(fmaf(an.x - am.x, inv, bb.x), 0.f);
                hv[1] = fmaxf(fmaf(an.y - am.y, inv, bb.y), 0.f);
                hv[2] = fmaxf(fmaf(an.z - am.z, inv, bb.z), 0.f);
                hv[3] = fmaxf(fmaf(an.w - am.w, inv, bb.w), 0.f);
#pragma unroll
                for (int u = 0; u < 4; ++u) {
                    const float4 w2a = *(const float4*)&w2_s[jj0 + u][0];
                    const float4 w2b = *(const float4*)&w2_s[jj0 + u][4];
                    acc8[0] = fmaf(hv[u], w2a.x, acc8[0]);
                    acc8[1] = fmaf(hv[u], w2a.y, acc8[1]);
                    acc8[2] = fmaf(hv[u], w2a.z, acc8[2]);
                    acc8[3] = fmaf(hv[u], w2a.w, acc8[3]);
                    acc8[4] = fmaf(hv[u], w2b.x, acc8[4]);
                    acc8[5] = fmaf(hv[u], w2b.y, acc8[5]);
                    acc8[6] = fmaf(hv[u], w2b.z, acc8[6]);
                    acc8[7] = fmaf(hv[u], w2b.w, acc8[7]);
                }
            }
#pragma unroll
            for (int h = 0; h < 8; ++h) bias_s[h][i][j] = acc8[h];
        }
        __syncthreads();

        // ---- per-wave QK^T (lane = key j), q pre-scaled by 1/8 ----
        float s_acc[16];
#pragma unroll
        for (int i = 0; i < 16; ++i) s_acc[i] = 0.f;
        const float* kp = kTb + m0;
        for (int d0 = 0; d0 < 64; d0 += 4) {
            const float k0v = kp[(size_t)(d0 + 0) * 1024];
            const float k1v = kp[(size_t)(d0 + 1) * 1024];
            const float k2v = kp[(size_t)(d0 + 2) * 1024];
            const float k3v = kp[(size_t)(d0 + 3) * 1024];
#pragma unroll
            for (int i = 0; i < 16; ++i) {
                const float4 q4 = *(const float4*)&q_s[w][i][d0];
                s_acc[i] = fmaf(q4.x, k0v, s_acc[i]);
                s_acc[i] = fmaf(q4.y, k1v, s_acc[i]);
                s_acc[i] = fmaf(q4.z, k2v, s_acc[i]);
                s_acc[i] = fmaf(q4.w, k3v, s_acc[i]);
            }
        }

        // ---- online softmax; p overwrites bias_s in place ----
#pragma unroll
        for (int i = 0; i < 16; ++i) {
            const float sv = s_acc[i] + bias_s[w][i][lane];
            float mx = sv;
#pragma unroll
            for (int off = 32; off > 0; off >>= 1)
                mx = fmaxf(mx, __shfl_xor(mx, off, 64));
            const float mnew = fmaxf(m_i[i], mx);
            const float p = __expf(sv - mnew);
            float rs = p;
#pragma unroll
            for (int off = 32; off > 0; off >>= 1) rs += __shfl_xor(rs, off, 64);
            const float alpha = __expf(m_i[i] - mnew);
            l_i[i] = fmaf(l_i[i], alpha, rs);
            o_acc[i] *= alpha;
            m_i[i] = mnew;
            bias_s[w][i][lane] = p;   // in-place: bias slot becomes p
        }

        // ---- per-wave PV (lane = output dim d) ----
        const float* vp = vb + (size_t)m0 * 64;
        for (int j0 = 0; j0 < 64; j0 += 4) {
            const float v0 = vp[(size_t)(j0 + 0) * 64];
            const float v1 = vp[(size_t)(j0 + 1) * 64];
            const float v2 = vp[(size_t)(j0 + 2) * 64];
            const float v3 = vp[(size_t)(j0 + 3) * 64];
#pragma unroll
            for (int i = 0; i < 16; ++i) {
                const float4 p4 = *(const float4*)&bias_s[w][i][j0];
                o_acc[i] = fmaf(p4.x, v0, o_acc[i]);
                o_acc[i] = fmaf(p4.y, v1, o_acc[i]);
                o_acc[i] = fmaf(p4.z, v2, o_acc[i]);
                o_acc[i] = fmaf(p4.w, v3, o_acc[i]);
            }
        }
    }

    // ---- epilogue ----
#pragma unroll
    for (int i = 0; i < 16; ++i) {
        out[(size_t)(b * 1024 + nq0 + i) * 512 + w * 64 + lane] =
            o_acc[i] / l_i[i];
    }
}

extern "C" void kernel_launch(void* const* d_in, const int* in_sizes, int n_in,
                              void* d_out, int out_size, void* d_ws, size_t ws_size,
                              hipStream_t stream) {
    const float* x    = (const float*)d_in[0];
    const float* pos  = (const float*)d_in[1];
    const float* wqkv = (const float*)d_in[2];
    const float* bqkv = (const float*)d_in[3];
    const float* w1   = (const float*)d_in[4];
    const float* b1   = (const float*)d_in[5];
    const float* w2   = (const float*)d_in[6];
    const float* b2   = (const float*)d_in[7];
    float* out = (float*)d_out;
    float* ws = (float*)d_ws;

    float* q    = ws;             // 2,097,152 floats
    float* kT   = ws + 2097152;   // 2,097,152
    float* v    = ws + 4194304;   // 2,097,152
    float* apos = ws + 6291456;   // 262,144   (total 25.2 MB)
    float* kk   = out;            // d_out as scratch for untransposed k

    hipLaunchKernelGGL(pos_w1_kernel, dim3(1024), dim3(256), 0, stream,
                       pos, w1, apos);
    hipLaunchKernelGGL(qkv_gemm, dim3(32, 12), dim3(256), 0, stream,
                       x, wqkv, bqkv, q, kk, v);
    hipLaunchKernelGGL(kt_transpose, dim3(32, 16), dim3(256), 0, stream,
                       kk, kT);
    hipLaunchKernelGGL(attn_fused, dim3(256), dim3(512), 0, stream,
                       q, kT, v, apos, pos, b1, w2, b2, out);
}

// Round 3
// 295.947 us; speedup vs baseline: 4.4386x; 4.2285x over previous
//
#include <hip/hip_runtime.h>
#include <hip/hip_bf16.h>
#include <math.h>

// B=4, N=1024, C=512, H=8, D=64
// ws: qb[2M bf16] | kb[2M bf16] | vb[2M bf16] | vTb[2M bf16] | apos[256K f32] = 17 MB
// R2 -> R3: MFMA (bf16) for bias-MLP@w2, QK^T, PV. fp32 qkv GEMM kept.

typedef __attribute__((ext_vector_type(8))) short bh8;   // 8 bf16 in 4 VGPRs
typedef __attribute__((ext_vector_type(4))) float f32x4;

static __device__ __forceinline__ ushort f2bf(float x) {
    __hip_bfloat16 h = __float2bfloat16(x);
    return *reinterpret_cast<ushort*>(&h);
}
static __device__ __forceinline__ float bf2f(ushort u) {
    unsigned v = ((unsigned)u) << 16;
    return __builtin_bit_cast(float, v);
}

// ---------------- kernel 0: apos = pos @ w1 (fp32) ----------------
__global__ __launch_bounds__(256) void pos_w1_kernel(
    const float* __restrict__ pos, const float* __restrict__ w1,
    float* __restrict__ apos)
{
    const int idx = blockIdx.x * 256 + threadIdx.x;   // < 4096*64
    const int bn = idx >> 6, j = idx & 63;
    const float px = pos[bn * 3 + 0];
    const float py = pos[bn * 3 + 1];
    const float pz = pos[bn * 3 + 2];
    apos[idx] = fmaf(px, w1[j], fmaf(py, w1[64 + j], pz * w1[128 + j]));
}

// ---------------- kernel 1: qkv GEMM (fp32 compute, bf16 out) ----------------
// q stored pre-scaled by 0.125. q,k,v all [B,H,N,D] row-major bf16.
__global__ __launch_bounds__(256) void qkv_gemm(
    const float* __restrict__ x, const float* __restrict__ wqkv,
    const float* __restrict__ bqkv,
    ushort* __restrict__ qb, ushort* __restrict__ kb, ushort* __restrict__ vb)
{
    __shared__ __align__(16) float As[8][128];
    __shared__ __align__(16) float Bs[8][128];
    const int tid = threadIdx.x;
    const int m0 = blockIdx.x * 128;
    const int n0 = blockIdx.y * 128;
    const int tx = tid & 15;
    const int ty = tid >> 4;
    const int ar = tid >> 1, ak = (tid & 1) * 4;
    const int br = tid >> 5, bc = (tid & 31) * 4;

    float acc[8][8];
#pragma unroll
    for (int r = 0; r < 8; ++r)
#pragma unroll
        for (int c = 0; c < 8; ++c) acc[r][c] = 0.f;

    for (int k0 = 0; k0 < 512; k0 += 8) {
        const float4 av = *(const float4*)&x[(size_t)(m0 + ar) * 512 + k0 + ak];
        const float4 bv = *(const float4*)&wqkv[(size_t)(k0 + br) * 1536 + n0 + bc];
        __syncthreads();
        As[ak + 0][ar] = av.x;
        As[ak + 1][ar] = av.y;
        As[ak + 2][ar] = av.z;
        As[ak + 3][ar] = av.w;
        *(float4*)&Bs[br][bc] = bv;
        __syncthreads();
#pragma unroll
        for (int kk = 0; kk < 8; ++kk) {
            const float4 a0 = *(const float4*)&As[kk][ty * 8];
            const float4 a1 = *(const float4*)&As[kk][ty * 8 + 4];
            const float4 b0 = *(const float4*)&Bs[kk][tx * 8];
            const float4 b1v = *(const float4*)&Bs[kk][tx * 8 + 4];
            const float ar_[8] = {a0.x, a0.y, a0.z, a0.w, a1.x, a1.y, a1.z, a1.w};
            const float bc_[8] = {b0.x, b0.y, b0.z, b0.w, b1v.x, b1v.y, b1v.z, b1v.w};
#pragma unroll
            for (int r = 0; r < 8; ++r)
#pragma unroll
                for (int c = 0; c < 8; ++c)
                    acc[r][c] = fmaf(ar_[r], bc_[c], acc[r][c]);
        }
    }

#pragma unroll
    for (int r = 0; r < 8; ++r) {
        const int row = m0 + ty * 8 + r;
        const int b = row >> 10, n = row & 1023;
#pragma unroll
        for (int c = 0; c < 8; ++c) {
            const int col = n0 + tx * 8 + c;
            const float val = acc[r][c] + bqkv[col];
            const int s = col >> 9;
            const int h = (col >> 6) & 7;
            const int d = col & 63;
            const size_t off = (size_t)((b * 8 + h) * 1024 + n) * 64 + d;
            if (s == 0)
                qb[off] = f2bf(val * 0.125f);   // fold softmax scale into q
            else if (s == 1)
                kb[off] = f2bf(val);
            else
                vb[off] = f2bf(val);
        }
    }
}

// ---------------- kernel 1b: vT[b,h,d,n] = v[b,h,n,d] (bf16) ----------------
__global__ __launch_bounds__(256) void vt_transpose(
    const ushort* __restrict__ vb, ushort* __restrict__ vT)
{
    __shared__ ushort tile[64][66];
    const int bh = blockIdx.x;          // 0..31
    const int n0 = blockIdx.y * 64;     // 0..960
    const int tid = threadIdx.x;
    const int c = tid & 63;
    const int r4 = tid >> 6;            // 0..3
    const size_t base = (size_t)bh * 65536;
#pragma unroll
    for (int rr = 0; rr < 16; ++rr) {
        const int row = rr * 4 + r4;
        tile[row][c] = vb[base + (size_t)(n0 + row) * 64 + c];
    }
    __syncthreads();
#pragma unroll
    for (int ww = 0; ww < 16; ++ww) {
        const int d = ww * 4 + r4;
        vT[base + (size_t)d * 1024 + n0 + c] = tile[c][d];
    }
}

// ---------------- kernel 2: fused bias-MLP + flash attention (MFMA) ----------
// block = (batch, 16-query tile); 8 waves, wave w == head w; key tiles of 64.
// Lane roles: lq = lane&15 (query / A-row / B-col), g = lane>>4 (k-chunk).
__global__ __launch_bounds__(512, 2) void attn_fused(
    const ushort* __restrict__ qb, const ushort* __restrict__ kb,
    const ushort* __restrict__ vTb, const float* __restrict__ apos,
    const float* __restrict__ pos, const float* __restrict__ b1,
    const float* __restrict__ w2, const float* __restrict__ b2,
    float* __restrict__ out)
{
    const int bx = blockIdx.x;          // 0..255
    const int xcd = bx & 7;             // XCD swizzle: 2 XCDs per batch -> KV L2-resident
    const int slot = bx >> 3;
    const int b = xcd >> 1;
    const int nq0 = (slot * 2 + (xcd & 1)) * 16;

    const int tid = threadIdx.x;
    const int w = tid >> 6;             // wave id == head
    const int lane = tid & 63;
    const int lq = lane & 15;
    const int g = lane >> 4;

    __shared__ __align__(16) float a_m_s[2][64][64];       // 32 KB (dbuf)
    __shared__ __align__(16) float pos_k_s[2][64][4];      // 2 KB
    __shared__ __align__(16) float bias_raw[8 * 1092 + 4]; // 35 KB, head-stride 1092 (bank-rotated)
    __shared__ __align__(16) ushort p_lds[8][16][80];      // 20.5 KB (wave-private P)
    __shared__ float red_s[8][20];                         // alpha / l broadcast

    // ---- per-lane loop-invariant registers ----
    float a_n[16], b1r[16];
    {
        const float* anp = apos + (size_t)(b * 1024 + nq0 + lq) * 64;
        *(float4*)&a_n[0]  = *(const float4*)&anp[g * 8];
        *(float4*)&a_n[4]  = *(const float4*)&anp[g * 8 + 4];
        *(float4*)&a_n[8]  = *(const float4*)&anp[32 + g * 8];
        *(float4*)&a_n[12] = *(const float4*)&anp[32 + g * 8 + 4];
        *(float4*)&b1r[0]  = *(const float4*)&b1[g * 8];
        *(float4*)&b1r[4]  = *(const float4*)&b1[g * 8 + 4];
        *(float4*)&b1r[8]  = *(const float4*)&b1[32 + g * 8];
        *(float4*)&b1r[12] = *(const float4*)&b1[32 + g * 8 + 4];
    }
    const float px = pos[(size_t)(b * 1024 + nq0 + lq) * 3 + 0];
    const float py = pos[(size_t)(b * 1024 + nq0 + lq) * 3 + 1];
    const float pz = pos[(size_t)(b * 1024 + nq0 + lq) * 3 + 2];

    bh8 w2fa, w2fb;                     // w2 B-frags: col = head = lq (cols 8..15 zero)
#pragma unroll
    for (int e = 0; e < 8; ++e) {
        const int k0 = g * 8 + e, k1 = 32 + g * 8 + e;
        w2fa[e] = (short)((lq < 8) ? f2bf(w2[k0 * 8 + lq]) : 0);
        w2fb[e] = (short)((lq < 8) ? f2bf(w2[k1 * 8 + lq]) : 0);
    }
    const float b2r = (lq < 8) ? b2[lq] : 0.f;

    bh8 qf0, qf1;                       // Q B-frags (pre-scaled 0.125)
    {
        const ushort* qp = qb + ((size_t)(b * 8 + w) * 1024 + nq0 + lq) * 64;
        qf0 = *(const bh8*)&qp[g * 8];
        qf1 = *(const bh8*)&qp[32 + g * 8];
    }

    f32x4 o[4];
#pragma unroll
    for (int dt = 0; dt < 4; ++dt) o[dt] = (f32x4){0.f, 0.f, 0.f, 0.f};
    float m_run = -INFINITY, l_run = 0.f;

#define STAGE(bufi, m0v) do { \
        const float4* _src = (const float4*)(apos + (size_t)(b * 1024 + (m0v)) * 64); \
        float4* _dst = (float4*)&a_m_s[bufi][0][0]; \
        _dst[tid] = _src[tid]; \
        _dst[tid + 512] = _src[tid + 512]; \
        if (tid < 192) pos_k_s[bufi][tid / 3][tid % 3] = \
            pos[(size_t)(b * 1024 + (m0v) + tid / 3) * 3 + tid % 3]; \
    } while (0)

    STAGE(0, 0);
    __syncthreads();

    for (int t16 = 0; t16 < 16; ++t16) {
        const int m0 = t16 * 64;
        const int buf = t16 & 1;

        // ---- bias MLP: wave w computes keys jl=w*8..w*8+7, ALL heads, via MFMA ----
#pragma unroll
        for (int kk = 0; kk < 8; ++kk) {
            const int jl = w * 8 + kk;
            const float kx = pos_k_s[buf][jl][0];
            const float ky = pos_k_s[buf][jl][1];
            const float kz = pos_k_s[buf][jl][2];
            const float dx = px - kx, dy = py - ky, dz = pz - kz;
            const float inv =
                1.f / (sqrtf(fmaf(dx, dx, fmaf(dy, dy, dz * dz))) + 1e-6f);
            const float* am = &a_m_s[buf][jl][0];   // broadcast reads
            bh8 hf0, hf1;
#pragma unroll
            for (int e = 0; e < 8; ++e) {
                const float h0 =
                    fmaxf(fmaf(a_n[e] - am[g * 8 + e], inv, b1r[e]), 0.f);
                const float h1 =
                    fmaxf(fmaf(a_n[8 + e] - am[32 + g * 8 + e], inv, b1r[8 + e]), 0.f);
                hf0[e] = (short)f2bf(h0);
                hf1[e] = (short)f2bf(h1);
            }
            f32x4 acc = (f32x4){0.f, 0.f, 0.f, 0.f};
            acc = __builtin_amdgcn_mfma_f32_16x16x32_bf16(hf0, w2fa, acc, 0, 0, 0);
            acc = __builtin_amdgcn_mfma_f32_16x16x32_bf16(hf1, w2fb, acc, 0, 0, 0);
            if (lq < 8) {   // D: col=lq=head, row=g*4+r=query
#pragma unroll
                for (int r = 0; r < 4; ++r)
                    bias_raw[lq * 1092 + (g * 4 + r) * 68 + jl] = acc[r] + b2r;
            }
        }
        __syncthreads();   // bias_raw visible cross-wave

        if (t16 < 15) STAGE(buf ^ 1, m0 + 64);   // prefetch next a_m/pos_k

        // ---- S^T = mfma(K_tile, Q^T): D col=lq=query, row=g*4+r=key-local ----
        const ushort* kbp = kb + ((size_t)(b * 8 + w) * 1024 + m0) * 64;
        f32x4 s[4];
#pragma unroll
        for (int at = 0; at < 4; ++at) {
            const bh8 kf0 = *(const bh8*)&kbp[(at * 16 + lq) * 64 + g * 8];
            const bh8 kf1 = *(const bh8*)&kbp[(at * 16 + lq) * 64 + 32 + g * 8];
            f32x4 z = (f32x4){0.f, 0.f, 0.f, 0.f};
            z = __builtin_amdgcn_mfma_f32_16x16x32_bf16(kf0, qf0, z, 0, 0, 0);
            s[at] = __builtin_amdgcn_mfma_f32_16x16x32_bf16(kf1, qf1, z, 0, 0, 0);
        }

        // ---- online softmax (keys split over g and regs; reduce over lanes ^16,^32) ----
        float sv[16];
        float pmax = -INFINITY;
#pragma unroll
        for (int at = 0; at < 4; ++at) {
            const float4 bv = *(const float4*)
                &bias_raw[w * 1092 + lq * 68 + at * 16 + g * 4];
            sv[at * 4 + 0] = s[at][0] + bv.x;
            sv[at * 4 + 1] = s[at][1] + bv.y;
            sv[at * 4 + 2] = s[at][2] + bv.z;
            sv[at * 4 + 3] = s[at][3] + bv.w;
#pragma unroll
            for (int r = 0; r < 4; ++r) pmax = fmaxf(pmax, sv[at * 4 + r]);
        }
        pmax = fmaxf(pmax, __shfl_xor(pmax, 16));
        pmax = fmaxf(pmax, __shfl_xor(pmax, 32));
        const float mnew = fmaxf(m_run, pmax);
        const float alpha = __expf(m_run - mnew);
        m_run = mnew;

        float rs = 0.f;
        ushort pb[16];
#pragma unroll
        for (int i = 0; i < 16; ++i) {
            const float p = __expf(sv[i] - mnew);
            pb[i] = f2bf(p);
            rs += bf2f(pb[i]);   // denominator matches bf16 numerator
        }
        rs += __shfl_xor(rs, 16);
        rs += __shfl_xor(rs, 32);
        l_run = l_run * alpha + rs;

#pragma unroll
        for (int at = 0; at < 4; ++at) {   // P -> wave-private LDS (no barrier)
            uint2 uv;
            uv.x = (unsigned)pb[at * 4 + 0] | ((unsigned)pb[at * 4 + 1] << 16);
            uv.y = (unsigned)pb[at * 4 + 2] | ((unsigned)pb[at * 4 + 3] << 16);
            *(uint2*)&p_lds[w][lq][at * 16 + g * 4] = uv;
        }
        red_s[w][lq] = alpha;

        float ar[4];
#pragma unroll
        for (int r = 0; r < 4; ++r) ar[r] = red_s[w][g * 4 + r];
#pragma unroll
        for (int dt = 0; dt < 4; ++dt) {
            o[dt][0] *= ar[0]; o[dt][1] *= ar[1];
            o[dt][2] *= ar[2]; o[dt][3] *= ar[3];
        }

        // ---- PV = mfma(P, V^T-frags): D col=lq=d-local, row=g*4+r=query ----
        const bh8 pa0 = *(const bh8*)&p_lds[w][lq][g * 8];
        const bh8 pa1 = *(const bh8*)&p_lds[w][lq][32 + g * 8];
        const ushort* vtp = vTb + ((size_t)(b * 8 + w) * 64) * 1024 + m0;
#pragma unroll
        for (int dt = 0; dt < 4; ++dt) {
            const bh8 vf0 = *(const bh8*)&vtp[(dt * 16 + lq) * 1024 + g * 8];
            const bh8 vf1 = *(const bh8*)&vtp[(dt * 16 + lq) * 1024 + 32 + g * 8];
            o[dt] = __builtin_amdgcn_mfma_f32_16x16x32_bf16(pa0, vf0, o[dt], 0, 0, 0);
            o[dt] = __builtin_amdgcn_mfma_f32_16x16x32_bf16(pa1, vf1, o[dt], 0, 0, 0);
        }
        __syncthreads();   // bias_raw reads done; next tile may overwrite
    }

    // ---- epilogue: out[b, nq0+q', w*64 + dt*16+lq] = o/l ----
    red_s[w][lq] = l_run;
    float li[4];
#pragma unroll
    for (int r = 0; r < 4; ++r) li[r] = 1.f / red_s[w][g * 4 + r];
#pragma unroll
    for (int dt = 0; dt < 4; ++dt)
#pragma unroll
        for (int r = 0; r < 4; ++r)
            out[(size_t)(b * 1024 + nq0 + g * 4 + r) * 512 + w * 64 + dt * 16 + lq] =
                o[dt][r] * li[r];
#undef STAGE
}

extern "C" void kernel_launch(void* const* d_in, const int* in_sizes, int n_in,
                              void* d_out, int out_size, void* d_ws, size_t ws_size,
                              hipStream_t stream) {
    const float* x    = (const float*)d_in[0];
    const float* pos  = (const float*)d_in[1];
    const float* wqkv = (const float*)d_in[2];
    const float* bqkv = (const float*)d_in[3];
    const float* w1   = (const float*)d_in[4];
    const float* b1   = (const float*)d_in[5];
    const float* w2   = (const float*)d_in[6];
    const float* b2   = (const float*)d_in[7];
    float* out = (float*)d_out;

    ushort* qb  = (ushort*)d_ws;            // 2,097,152 bf16
    ushort* kb  = qb + 2097152;
    ushort* vb  = kb + 2097152;
    ushort* vTb = vb + 2097152;
    float* apos = (float*)(vTb + 2097152);  // 262,144 f32  (17 MB total)

    hipLaunchKernelGGL(pos_w1_kernel, dim3(1024), dim3(256), 0, stream,
                       pos, w1, apos);
    hipLaunchKernelGGL(qkv_gemm, dim3(32, 12), dim3(256), 0, stream,
                       x, wqkv, bqkv, qb, kb, vb);
    hipLaunchKernelGGL(vt_transpose, dim3(32, 16), dim3(256), 0, stream,
                       vb, vTb);
    hipLaunchKernelGGL(attn_fused, dim3(256), dim3(512), 0, stream,
                       qb, kb, vTb, apos, pos, b1, w2, b2, out);
}

// Round 5
// 204.422 us; speedup vs baseline: 6.4259x; 1.4477x over previous
//
#include <hip/hip_runtime.h>
#include <hip/hip_bf16.h>
#include <math.h>

// B=4, N=1024, C=512, H=8, D=64
// ws layout (bytes), total 24 MB (<= 26.2 MB proven in R1):
//   qb  us  @ 0          (4,194,304)
//   kb  us  @ 4194304    (4,194,304)
//   vTb us  @ 8388608    (4,194,304)
//   apos f32@ 12582912   (1,048,576)
//   xh  us  @ 13631488   (4,194,304)  \ reused after qkv_mfma as
//   xl  us  @ 17825792   (4,194,304)  / outp1 f32 (8,388,608)
//   wTh us  @ 22020096   (1,572,864)  \ reused after qkv_mfma as
//   wTl us  @ 23592960   (1,572,864)  / ml0,ml1 f32 (262,144 each)
// d_out doubles as outp0 (unnormalized half-0 attention output).

typedef __attribute__((ext_vector_type(8))) short bh8;   // 8 bf16 in 4 VGPRs
typedef __attribute__((ext_vector_type(4))) float f32x4;

static __device__ __forceinline__ ushort f2bf(float x) {
    __hip_bfloat16 h = __float2bfloat16(x);
    return *reinterpret_cast<ushort*>(&h);
}
static __device__ __forceinline__ float bf2f(ushort u) {
    unsigned v = ((unsigned)u) << 16;
    return __builtin_bit_cast(float, v);
}

// ---------------- kernel 0: apos = pos @ w1 (fp32) ----------------
__global__ __launch_bounds__(256) void pos_w1_kernel(
    const float* __restrict__ pos, const float* __restrict__ w1,
    float* __restrict__ apos)
{
    const int idx = blockIdx.x * 256 + threadIdx.x;   // < 4096*64
    const int bn = idx >> 6, j = idx & 63;
    const float px = pos[bn * 3 + 0];
    const float py = pos[bn * 3 + 1];
    const float pz = pos[bn * 3 + 2];
    apos[idx] = fmaf(px, w1[j], fmaf(py, w1[64 + j], pz * w1[128 + j]));
}

// ---------------- kernel 0b: split x -> xh + xl (bf16 pair) ----------------
__global__ __launch_bounds__(256) void cast_x_split(
    const float* __restrict__ x, ushort* __restrict__ xh, ushort* __restrict__ xl)
{
    const int idx = blockIdx.x * 256 + threadIdx.x;   // < 524288
    const float4 v = *(const float4*)&x[(size_t)idx * 4];
    ushort h0 = f2bf(v.x), h1 = f2bf(v.y), h2 = f2bf(v.z), h3 = f2bf(v.w);
    ushort l0 = f2bf(v.x - bf2f(h0)), l1 = f2bf(v.y - bf2f(h1));
    ushort l2 = f2bf(v.z - bf2f(h2)), l3 = f2bf(v.w - bf2f(h3));
    uint2 hu, lu;
    hu.x = (unsigned)h0 | ((unsigned)h1 << 16);
    hu.y = (unsigned)h2 | ((unsigned)h3 << 16);
    lu.x = (unsigned)l0 | ((unsigned)l1 << 16);
    lu.y = (unsigned)l2 | ((unsigned)l3 << 16);
    *(uint2*)&xh[(size_t)idx * 4] = hu;
    *(uint2*)&xl[(size_t)idx * 4] = lu;
}

// ------------- kernel 0c: wT (transpose + hi/lo split) [1536][512] -----------
__global__ __launch_bounds__(256) void cast_wT_split(
    const float* __restrict__ w, ushort* __restrict__ wTh, ushort* __restrict__ wTl)
{
    __shared__ float t[64][65];
    const int n0 = blockIdx.x * 64;    // 0..1472
    const int k0 = blockIdx.y * 64;    // 0..448
    const int tid = threadIdx.x;
    const int c = tid & 63, r4 = tid >> 6;
#pragma unroll
    for (int i = 0; i < 16; ++i) {
        const int r = i * 4 + r4;      // k-local
        t[r][c] = w[(size_t)(k0 + r) * 1536 + n0 + c];
    }
    __syncthreads();
#pragma unroll
    for (int i = 0; i < 16; ++i) {
        const int r = i * 4 + r4;      // n-local
        const float v = t[c][r];
        const ushort hv = f2bf(v);
        wTh[(size_t)(n0 + r) * 512 + k0 + c] = hv;
        wTl[(size_t)(n0 + r) * 512 + k0 + c] = f2bf(v - bf2f(hv));
    }
}

// ---------------- kernel 1: qkv GEMM via split-bf16 MFMA ---------------------
// C = xh*wh + xh*wl + xl*wh (fp32 acc) + bias; outputs q (scaled 1/8), k, vT.
__global__ __launch_bounds__(256, 2) void qkv_mfma(
    const ushort* __restrict__ xh, const ushort* __restrict__ xl,
    const ushort* __restrict__ wTh, const ushort* __restrict__ wTl,
    const float* __restrict__ bqkv,
    ushort* __restrict__ qb, ushort* __restrict__ kb, ushort* __restrict__ vTb)
{
    __shared__ ushort Ah[128 * 68], Al[128 * 68], Bh[128 * 68], Bl[128 * 68];
    const int tid = threadIdx.x;
    const int m0 = blockIdx.x * 128;
    const int n0 = blockIdx.y * 128;
    const int wid = tid >> 6, lane = tid & 63;
    const int wr = wid >> 1, wc = wid & 1;
    const int lq = lane & 15, g = lane >> 4;

    f32x4 acc[4][4];
#pragma unroll
    for (int m = 0; m < 4; ++m)
#pragma unroll
        for (int n = 0; n < 4; ++n) acc[m][n] = (f32x4){0.f, 0.f, 0.f, 0.f};

    const int srow = tid >> 3;
    const int sc8 = (tid & 7) * 8;

    for (int kt = 0; kt < 8; ++kt) {
        const int kk0 = kt * 64;
        __syncthreads();
#pragma unroll
        for (int i = 0; i < 4; ++i) {
            const int row = i * 32 + srow;
            *(bh8*)&Ah[row * 68 + sc8] =
                *(const bh8*)&xh[(size_t)(m0 + row) * 512 + kk0 + sc8];
            *(bh8*)&Al[row * 68 + sc8] =
                *(const bh8*)&xl[(size_t)(m0 + row) * 512 + kk0 + sc8];
            *(bh8*)&Bh[row * 68 + sc8] =
                *(const bh8*)&wTh[(size_t)(n0 + row) * 512 + kk0 + sc8];
            *(bh8*)&Bl[row * 68 + sc8] =
                *(const bh8*)&wTl[(size_t)(n0 + row) * 512 + kk0 + sc8];
        }
        __syncthreads();
#pragma unroll
        for (int kc = 0; kc < 2; ++kc) {
            const int ko = kc * 32 + g * 8;
            bh8 afh[4], afl[4], bfh[4], bfl[4];
#pragma unroll
            for (int m = 0; m < 4; ++m) {
                afh[m] = *(const bh8*)&Ah[(wr * 64 + m * 16 + lq) * 68 + ko];
                afl[m] = *(const bh8*)&Al[(wr * 64 + m * 16 + lq) * 68 + ko];
            }
#pragma unroll
            for (int n = 0; n < 4; ++n) {
                bfh[n] = *(const bh8*)&Bh[(wc * 64 + n * 16 + lq) * 68 + ko];
                bfl[n] = *(const bh8*)&Bl[(wc * 64 + n * 16 + lq) * 68 + ko];
            }
#pragma unroll
            for (int m = 0; m < 4; ++m)
#pragma unroll
                for (int n = 0; n < 4; ++n) {
                    acc[m][n] = __builtin_amdgcn_mfma_f32_16x16x32_bf16(
                        afh[m], bfh[n], acc[m][n], 0, 0, 0);
                    acc[m][n] = __builtin_amdgcn_mfma_f32_16x16x32_bf16(
                        afh[m], bfl[n], acc[m][n], 0, 0, 0);
                    acc[m][n] = __builtin_amdgcn_mfma_f32_16x16x32_bf16(
                        afl[m], bfh[n], acc[m][n], 0, 0, 0);
                }
        }
    }

    // ---- epilogue: D col=lq (output col), row=g*4+r (x-row) ----
    const int s = n0 >> 9;              // 0:q 1:k 2:v (uniform per block)
    const int rowB = m0 + wr * 64;
    const int b = rowB >> 10;           // uniform
#pragma unroll
    for (int nt = 0; nt < 4; ++nt) {
        const int col = n0 + wc * 64 + nt * 16 + lq;
        const float bias_v = bqkv[col];
        const int h = (col >> 6) & 7, d = col & 63;
#pragma unroll
        for (int mt = 0; mt < 4; ++mt) {
            const int nloc = (rowB & 1023) + mt * 16 + g * 4;
            const float v0 = acc[mt][nt][0] + bias_v;
            const float v1 = acc[mt][nt][1] + bias_v;
            const float v2 = acc[mt][nt][2] + bias_v;
            const float v3 = acc[mt][nt][3] + bias_v;
            if (s == 0) {
                const size_t base = ((size_t)(b * 8 + h) * 1024 + nloc) * 64 + d;
                qb[base]       = f2bf(v0 * 0.125f);
                qb[base + 64]  = f2bf(v1 * 0.125f);
                qb[base + 128] = f2bf(v2 * 0.125f);
                qb[base + 192] = f2bf(v3 * 0.125f);
            } else if (s == 1) {
                const size_t base = ((size_t)(b * 8 + h) * 1024 + nloc) * 64 + d;
                kb[base]       = f2bf(v0);
                kb[base + 64]  = f2bf(v1);
                kb[base + 128] = f2bf(v2);
                kb[base + 192] = f2bf(v3);
            } else {
                uint2 u;
                u.x = (unsigned)f2bf(v0) | ((unsigned)f2bf(v1) << 16);
                u.y = (unsigned)f2bf(v2) | ((unsigned)f2bf(v3) << 16);
                *(uint2*)&vTb[((size_t)(b * 8 + h) * 64 + d) * 1024 + nloc] = u;
            }
        }
    }
}

// ---------------- kernel 2: fused bias-MLP + flash attention (key-split) -----
// 512 blocks = (batch, 16-query tile, key-half); 8 waves, wave w == head w.
__global__ __launch_bounds__(512, 4) void attn_fused(
    const ushort* __restrict__ qb, const ushort* __restrict__ kb,
    const ushort* __restrict__ vTb, const float* __restrict__ apos,
    const float* __restrict__ pos, const float* __restrict__ b1,
    const float* __restrict__ w2, const float* __restrict__ b2,
    float* __restrict__ outp0, float* __restrict__ outp1,
    float* __restrict__ ml0, float* __restrict__ ml1)
{
    const int bx = blockIdx.x;          // 0..511
    const int xcd = bx & 7;             // XCD swizzle: 2 XCDs per batch
    const int b = xcd >> 1;
    const int u = (bx >> 3) * 2 + (xcd & 1);  // 0..127
    const int nq0 = (u & 63) * 16;
    const int half = u >> 6;
    const int k0base = half * 512;

    float* __restrict__ outp = half ? outp1 : outp0;
    float* __restrict__ mlp  = half ? ml1 : ml0;

    const int tid = threadIdx.x;
    const int w = tid >> 6;             // wave id == head
    const int lane = tid & 63;
    const int lq = lane & 15;
    const int g = lane >> 4;

    __shared__ __align__(16) float a_m_s[64][64];          // 16 KB (single buf)
    __shared__ __align__(16) float pos_k_s[64][4];         // 1 KB
    __shared__ __align__(16) float bias_raw[8 * 1092 + 4]; // 35 KB
    __shared__ __align__(16) ushort p_lds[8][16][72];      // 18.4 KB
    __shared__ float red_s[8][20];                         // 0.64 KB  (~71 KB tot)

    // ---- per-lane loop-invariant registers ----
    float a_n[16], b1r[16];
    {
        const float* anp = apos + (size_t)(b * 1024 + nq0 + lq) * 64;
        *(float4*)&a_n[0]  = *(const float4*)&anp[g * 8];
        *(float4*)&a_n[4]  = *(const float4*)&anp[g * 8 + 4];
        *(float4*)&a_n[8]  = *(const float4*)&anp[32 + g * 8];
        *(float4*)&a_n[12] = *(const float4*)&anp[32 + g * 8 + 4];
        *(float4*)&b1r[0]  = *(const float4*)&b1[g * 8];
        *(float4*)&b1r[4]  = *(const float4*)&b1[g * 8 + 4];
        *(float4*)&b1r[8]  = *(const float4*)&b1[32 + g * 8];
        *(float4*)&b1r[12] = *(const float4*)&b1[32 + g * 8 + 4];
    }
    const float px = pos[(size_t)(b * 1024 + nq0 + lq) * 3 + 0];
    const float py = pos[(size_t)(b * 1024 + nq0 + lq) * 3 + 1];
    const float pz = pos[(size_t)(b * 1024 + nq0 + lq) * 3 + 2];

    bh8 w2fa, w2fb;                     // w2 B-frags: col = head = lq
#pragma unroll
    for (int e = 0; e < 8; ++e) {
        const int k0 = g * 8 + e, k1 = 32 + g * 8 + e;
        w2fa[e] = (short)((lq < 8) ? f2bf(w2[k0 * 8 + lq]) : 0);
        w2fb[e] = (short)((lq < 8) ? f2bf(w2[k1 * 8 + lq]) : 0);
    }
    const float b2r = (lq < 8) ? b2[lq] : 0.f;

    bh8 qf0, qf1;                       // Q B-frags (pre-scaled 0.125)
    {
        const ushort* qp = qb + ((size_t)(b * 8 + w) * 1024 + nq0 + lq) * 64;
        qf0 = *(const bh8*)&qp[g * 8];
        qf1 = *(const bh8*)&qp[32 + g * 8];
    }

    f32x4 o[4];
#pragma unroll
    for (int dt = 0; dt < 4; ++dt) o[dt] = (f32x4){0.f, 0.f, 0.f, 0.f};
    float m_run = -INFINITY, l_run = 0.f;

#define STAGE(m0v) do { \
        const float4* _src = (const float4*)(apos + (size_t)(b * 1024 + (m0v)) * 64); \
        float4* _dst = (float4*)&a_m_s[0][0]; \
        _dst[tid] = _src[tid]; \
        _dst[tid + 512] = _src[tid + 512]; \
        if (tid < 192) pos_k_s[tid / 3][tid % 3] = \
            pos[(size_t)(b * 1024 + (m0v) + tid / 3) * 3 + tid % 3]; \
    } while (0)

    STAGE(k0base);
    __syncthreads();

    for (int t16 = 0; t16 < 8; ++t16) {
        const int m0 = k0base + t16 * 64;

        // ---- bias MLP: wave w computes keys w*8..w*8+7, ALL heads, via MFMA ----
#pragma unroll
        for (int kk = 0; kk < 8; ++kk) {
            const int jl = w * 8 + kk;
            const float kx = pos_k_s[jl][0];
            const float ky = pos_k_s[jl][1];
            const float kz = pos_k_s[jl][2];
            const float dx = px - kx, dy = py - ky, dz = pz - kz;
            const float inv =
                1.f / (sqrtf(fmaf(dx, dx, fmaf(dy, dy, dz * dz))) + 1e-6f);
            const float* am = &a_m_s[jl][0];   // broadcast reads
            bh8 hf0, hf1;
#pragma unroll
            for (int e = 0; e < 8; ++e) {
                const float h0 =
                    fmaxf(fmaf(a_n[e] - am[g * 8 + e], inv, b1r[e]), 0.f);
                const float h1 =
                    fmaxf(fmaf(a_n[8 + e] - am[32 + g * 8 + e], inv, b1r[8 + e]), 0.f);
                hf0[e] = (short)f2bf(h0);
                hf1[e] = (short)f2bf(h1);
            }
            f32x4 acc = (f32x4){0.f, 0.f, 0.f, 0.f};
            acc = __builtin_amdgcn_mfma_f32_16x16x32_bf16(hf0, w2fa, acc, 0, 0, 0);
            acc = __builtin_amdgcn_mfma_f32_16x16x32_bf16(hf1, w2fb, acc, 0, 0, 0);
            if (lq < 8) {   // D: col=lq=head, row=g*4+r=query
#pragma unroll
                for (int r = 0; r < 4; ++r)
                    bias_raw[lq * 1092 + (g * 4 + r) * 68 + jl] = acc[r] + b2r;
            }
        }
        __syncthreads();   // bias_raw visible cross-wave; a_m reads done

        if (t16 < 7) STAGE(m0 + 64);   // single-buffer prefetch (safe: consumed
                                       // only after the tile-end barrier)

        // ---- S^T = mfma(K_tile, Q^T): D col=lq=query, row=g*4+r=key-local ----
        const ushort* kbp = kb + ((size_t)(b * 8 + w) * 1024 + m0) * 64;
        f32x4 s[4];
#pragma unroll
        for (int at = 0; at < 4; ++at) {
            const bh8 kf0 = *(const bh8*)&kbp[(at * 16 + lq) * 64 + g * 8];
            const bh8 kf1 = *(const bh8*)&kbp[(at * 16 + lq) * 64 + 32 + g * 8];
            f32x4 z = (f32x4){0.f, 0.f, 0.f, 0.f};
            z = __builtin_amdgcn_mfma_f32_16x16x32_bf16(kf0, qf0, z, 0, 0, 0);
            s[at] = __builtin_amdgcn_mfma_f32_16x16x32_bf16(kf1, qf1, z, 0, 0, 0);
        }

        // ---- online softmax (reduce over lanes ^16,^32) ----
        float sv[16];
        float pmax = -INFINITY;
#pragma unroll
        for (int at = 0; at < 4; ++at) {
            const float4 bv = *(const float4*)
                &bias_raw[w * 1092 + lq * 68 + at * 16 + g * 4];
            sv[at * 4 + 0] = s[at][0] + bv.x;
            sv[at * 4 + 1] = s[at][1] + bv.y;
            sv[at * 4 + 2] = s[at][2] + bv.z;
            sv[at * 4 + 3] = s[at][3] + bv.w;
#pragma unroll
            for (int r = 0; r < 4; ++r) pmax = fmaxf(pmax, sv[at * 4 + r]);
        }
        pmax = fmaxf(pmax, __shfl_xor(pmax, 16));
        pmax = fmaxf(pmax, __shfl_xor(pmax, 32));
        const float mnew = fmaxf(m_run, pmax);
        const float alpha = __expf(m_run - mnew);
        m_run = mnew;

        float rs = 0.f;
        ushort pb[16];
#pragma unroll
        for (int i = 0; i < 16; ++i) {
            const float p = __expf(sv[i] - mnew);
            pb[i] = f2bf(p);
            rs += bf2f(pb[i]);   // denominator matches bf16 numerator
        }
        rs += __shfl_xor(rs, 16);
        rs += __shfl_xor(rs, 32);
        l_run = l_run * alpha + rs;

#pragma unroll
        for (int at = 0; at < 4; ++at) {   // P -> wave-private LDS (no barrier)
            uint2 uv;
            uv.x = (unsigned)pb[at * 4 + 0] | ((unsigned)pb[at * 4 + 1] << 16);
            uv.y = (unsigned)pb[at * 4 + 2] | ((unsigned)pb[at * 4 + 3] << 16);
            *(uint2*)&p_lds[w][lq][at * 16 + g * 4] = uv;
        }
        red_s[w][lq] = alpha;

        float ar[4];
#pragma unroll
        for (int r = 0; r < 4; ++r) ar[r] = red_s[w][g * 4 + r];
#pragma unroll
        for (int dt = 0; dt < 4; ++dt) {
            o[dt][0] *= ar[0]; o[dt][1] *= ar[1];
            o[dt][2] *= ar[2]; o[dt][3] *= ar[3];
        }

        // ---- PV = mfma(P, V^T-frags): D col=lq=d-local, row=g*4+r=query ----
        const bh8 pa0 = *(const bh8*)&p_lds[w][lq][g * 8];
        const bh8 pa1 = *(const bh8*)&p_lds[w][lq][32 + g * 8];
        const ushort* vtp = vTb + ((size_t)(b * 8 + w) * 64) * 1024 + m0;
#pragma unroll
        for (int dt = 0; dt < 4; ++dt) {
            const bh8 vf0 = *(const bh8*)&vtp[(dt * 16 + lq) * 1024 + g * 8];
            const bh8 vf1 = *(const bh8*)&vtp[(dt * 16 + lq) * 1024 + 32 + g * 8];
            o[dt] = __builtin_amdgcn_mfma_f32_16x16x32_bf16(pa0, vf0, o[dt], 0, 0, 0);
            o[dt] = __builtin_amdgcn_mfma_f32_16x16x32_bf16(pa1, vf1, o[dt], 0, 0, 0);
        }
        __syncthreads();   // bias_raw reads + a_m writes done before next tile
    }

    // ---- epilogue: unnormalized o + (m,l) per query ----
    if (g == 0) {
        float2 mlv;
        mlv.x = m_run;
        mlv.y = l_run;
        *(float2*)&mlp[((size_t)(b * 8 + w) * 1024 + nq0 + lq) * 2] = mlv;
    }
#pragma unroll
    for (int dt = 0; dt < 4; ++dt)
#pragma unroll
        for (int r = 0; r < 4; ++r)
            outp[(size_t)(b * 1024 + nq0 + g * 4 + r) * 512 + w * 64 + dt * 16 + lq] =
                o[dt][r];
#undef STAGE
}

// ---------------- kernel 3: combine the two key-halves ----------------
__global__ __launch_bounds__(256) void combine_halves(
    const float* __restrict__ o0, const float* __restrict__ o1,
    const float* __restrict__ ml0, const float* __restrict__ ml1,
    float* __restrict__ outF)
{
    const int idx = blockIdx.x * 256 + threadIdx.x;   // < 524288
    const size_t c4 = (size_t)idx * 4;
    const int row = idx >> 7;            // b*1024+n
    const int coff = (idx & 127) * 4;
    const int h = coff >> 6;
    const int b = row >> 10, n = row & 1023;
    const size_t mli = ((size_t)(b * 8 + h) * 1024 + n) * 2;
    const float2 v0 = *(const float2*)&ml0[mli];
    const float2 v1 = *(const float2*)&ml1[mli];
    const float m = fmaxf(v0.x, v1.x);
    const float e0 = __expf(v0.x - m), e1 = __expf(v1.x - m);
    const float inv = 1.f / fmaf(v0.y, e0, v1.y * e1);
    const float4 a = *(const float4*)&o0[c4];
    const float4 bb = *(const float4*)&o1[c4];
    float4 r;
    r.x = fmaf(a.x, e0, bb.x * e1) * inv;
    r.y = fmaf(a.y, e0, bb.y * e1) * inv;
    r.z = fmaf(a.z, e0, bb.z * e1) * inv;
    r.w = fmaf(a.w, e0, bb.w * e1) * inv;
    *(float4*)&outF[c4] = r;
}

extern "C" void kernel_launch(void* const* d_in, const int* in_sizes, int n_in,
                              void* d_out, int out_size, void* d_ws, size_t ws_size,
                              hipStream_t stream) {
    const float* x    = (const float*)d_in[0];
    const float* pos  = (const float*)d_in[1];
    const float* wqkv = (const float*)d_in[2];
    const float* bqkv = (const float*)d_in[3];
    const float* w1   = (const float*)d_in[4];
    const float* b1   = (const float*)d_in[5];
    const float* w2   = (const float*)d_in[6];
    const float* b2   = (const float*)d_in[7];
    float* out = (float*)d_out;

    char* W = (char*)d_ws;
    ushort* qb    = (ushort*)W;
    ushort* kb    = (ushort*)(W + 4194304);
    ushort* vTb   = (ushort*)(W + 8388608);
    float*  apos  = (float*)(W + 12582912);
    ushort* xh    = (ushort*)(W + 13631488);
    ushort* xl    = (ushort*)(W + 17825792);
    float*  outp1 = (float*)(W + 13631488);   // aliases xh/xl (dead after qkv)
    ushort* wTh   = (ushort*)(W + 22020096);
    ushort* wTl   = (ushort*)(W + 23592960);
    float*  ml0   = (float*)(W + 22020096);   // aliases wTh (dead after qkv)
    float*  ml1   = (float*)(W + 22282240);
    float*  outp0 = out;                      // d_out as half-0 scratch

    hipLaunchKernelGGL(pos_w1_kernel, dim3(1024), dim3(256), 0, stream,
                       pos, w1, apos);
    hipLaunchKernelGGL(cast_x_split, dim3(2048), dim3(256), 0, stream,
                       x, xh, xl);
    hipLaunchKernelGGL(cast_wT_split, dim3(24, 8), dim3(256), 0, stream,
                       wqkv, wTh, wTl);
    hipLaunchKernelGGL(qkv_mfma, dim3(32, 12), dim3(256), 0, stream,
                       xh, xl, wTh, wTl, bqkv, qb, kb, vTb);
    hipLaunchKernelGGL(attn_fused, dim3(512), dim3(512), 0, stream,
                       qb, kb, vTb, apos, pos, b1, w2, b2,
                       outp0, outp1, ml0, ml1);
    hipLaunchKernelGGL(combine_halves, dim3(2048), dim3(256), 0, stream,
                       outp0, outp1, ml0, ml1, out);
}